// Round 5
// baseline (196.870 us; speedup 1.0000x reference)
//
#include <hip/hip_runtime.h>
#include <hip/hip_bf16.h>
#include <math.h>

#define NCLS 256
#define PER_CLASS 128
#define NSUP 5
#define NQRY 123              // PER_CLASS - NSUP
#define NVIEW 2
#define DD 384
#define NQ_TOT (NCLS * NQRY)  // 31488
#define QB 256                // queries per block (31488 = 123 * 256)
#define CQ 64                 // classes per quarter (blockIdx.z)
#define BK 32                 // k-tile (elems)
#define NKT (DD / BK)         // 12
#define INV_CNT (1.f / (float)(NQ_TOT * NVIEW))

typedef __attribute__((ext_vector_type(8))) short short8;
typedef __attribute__((ext_vector_type(4))) float floatx4;

union FragU { uint4 u; short8 s; };
union PkU { __hip_bfloat162 b2; unsigned int u; };

__device__ __forceinline__ unsigned int cvt2bf(float lo, float hi) {
    PkU p;
    p.b2 = __float22bfloat162_rn(make_float2(lo, hi));
    return p.u;
}

// async global->LDS, 16B per lane; LDS dest = wave-uniform base + lane*16 (HW rule)
__device__ __forceinline__ void gll16(const ushort* g, ushort* l) {
    __builtin_amdgcn_global_load_lds(
        (const __attribute__((address_space(1))) unsigned int*)g,
        (__attribute__((address_space(3))) unsigned int*)l, 16, 0, 0);
}

#define BARRIER() asm volatile("s_waitcnt lgkmcnt(0)\n\ts_barrier" ::: "memory")
#define WAITVM(n) asm volatile("s_waitcnt vmcnt(" #n ")" ::: "memory")

// ---------- kernel 1: prototypes -> bf16 + y2 + zero accumulators ----------
__global__ __launch_bounds__(384) void proto_kernel(const float* __restrict__ reps,
                                                    ushort* __restrict__ pbf,
                                                    float* __restrict__ y2,
                                                    float* __restrict__ wsc,
                                                    float* __restrict__ out) {
    __shared__ float wp[6];
    const int b = blockIdx.x;          // v*256 + c
    const int c = b & 255, v = b >> 8;
    const int d = threadIdx.x;         // 0..383
    if (b == 0 && d == 0) { out[0] = 0.f; wsc[0] = 0.f; }
    const float* p = reps + ((size_t)(c * PER_CLASS) * NVIEW + v) * DD + d;
    float s = 0.f;
#pragma unroll
    for (int k = 0; k < NSUP; ++k) s += p[(size_t)k * NVIEW * DD];
    s *= 0.2f;
    __hip_bfloat16 h = __float2bfloat16(s);
    pbf[(size_t)b * DD + d] = *reinterpret_cast<ushort*>(&h);
    float q = s * s;
#pragma unroll
    for (int o = 1; o < 64; o <<= 1) q += __shfl_xor(q, o);
    if ((d & 63) == 0) wp[d >> 6] = q;
    __syncthreads();
    if (d == 0) y2[b] = wp[0] + wp[1] + wp[2] + wp[3] + wp[4] + wp[5];
}

// ---------- kernel 2: BARRIER-FREE bf16 MFMA GEMM over a resident P-quarter ----------
// grid (123, NVIEW, 4): block = 256 queries x 64 classes (quarter zq), 512 threads.
// P-quarter (64 cls x 384 k, bf16, k-tile-major [12][64][32]) staged ONCE via gll
// (48 KB LDS, linear dest verified: lane l -> row sub*16+(l>>2), chunk l&3).
// K-loop has ZERO barriers: Q fragments per-lane from global (f32->bf16 in-reg,
// bit-identical to r0-r3 fragments), 3-buffer 2-tile register prefetch;
// B-frags from resident LDS (64 lanes -> 64 distinct 16B slots: conflict-free).
// Outputs per-(query,quarter) LSE partials {max,sumexp} + corr atomic.
__global__ __launch_bounds__(512) void main_kernel(const float* __restrict__ reps,
                                                   const ushort* __restrict__ pbf,
                                                   const float* __restrict__ y2g,
                                                   float* __restrict__ pmax_g,
                                                   float* __restrict__ pse_g,
                                                   float* __restrict__ wsc) {
    __shared__ ushort p_lds[NKT * CQ * 32];   // 49152 B

    const int t = threadIdx.x;
    const int v = blockIdx.y;
    const int zq = blockIdx.z;
    const int q0 = blockIdx.x * QB;
    const int wave = t >> 6;
    const int lane = t & 63;
    const int col = lane & 15;   // MFMA m/n index
    const int quad = lane >> 4;  // MFMA k-chunk / C row group

    // ---- stage P-quarter: 48 gll instrs total, 6 per wave ----
#pragma unroll
    for (int i = 0; i < 6; ++i) {
        const int g = wave * 6 + i;
        const int slab = g >> 2;        // k-tile 0..11
        const int sub = g & 3;          // 16-row group within the 64 classes
        const ushort* src = pbf +
            (size_t)(v * NCLS + zq * CQ + sub * 16 + (lane >> 2)) * DD +
            slab * BK + (lane & 3) * 8;
        gll16(src, &p_lds[slab * 2048 + sub * 512]);
    }

    // ---- Q per-lane fragment bases: row (q0 + wave*32 + mt*16 + col), floats quad*8.. ----
    const float* qb[2];
#pragma unroll
    for (int mt = 0; mt < 2; ++mt) {
        const int nq = q0 + wave * 32 + mt * 16 + col;
        qb[mt] = reps +
            (size_t)((nq / NQRY) * PER_CLASS + NSUP + (nq % NQRY)) * (NVIEW * DD) +
            v * DD + quad * 8;
    }

    floatx4 acc[2][4];
#pragma unroll
    for (int mt = 0; mt < 2; ++mt)
#pragma unroll
        for (int nt = 0; nt < 4; ++nt) acc[mt][nt] = (floatx4)0.f;

    float4 qv[3][2][2];   // [buf][mt][half] - static indices only (unrolled loop)

#define LOADQ(kt, b)                                                               \
    do {                                                                           \
        _Pragma("unroll") for (int mt = 0; mt < 2; ++mt) {                         \
            qv[b][mt][0] = *(const float4*)(qb[mt] + (kt) * BK);                   \
            qv[b][mt][1] = *(const float4*)(qb[mt] + (kt) * BK + 4);               \
        }                                                                          \
    } while (0)

    LOADQ(0, 0);
    LOADQ(1, 1);
    WAITVM(0);          // own gll batch + Q0/Q1 landed (prologue only)
    BARRIER();          // P-quarter visible to all waves -- the ONLY K-loop barrier

#pragma unroll
    for (int kt = 0; kt < NKT; ++kt) {
        if (kt + 2 < NKT) LOADQ(kt + 2, (kt + 2) % 3);
        short8 af[2];
#pragma unroll
        for (int mt = 0; mt < 2; ++mt) {
            FragU f;
            f.u.x = cvt2bf(qv[kt % 3][mt][0].x, qv[kt % 3][mt][0].y);
            f.u.y = cvt2bf(qv[kt % 3][mt][0].z, qv[kt % 3][mt][0].w);
            f.u.z = cvt2bf(qv[kt % 3][mt][1].x, qv[kt % 3][mt][1].y);
            f.u.w = cvt2bf(qv[kt % 3][mt][1].z, qv[kt % 3][mt][1].w);
            af[mt] = f.s;
        }
#pragma unroll
        for (int nt = 0; nt < 4; ++nt) {
            FragU bb;
            bb.u = *(const uint4*)&p_lds[kt * 2048 + (nt * 16 + col) * 32 + quad * 8];
#pragma unroll
            for (int mt = 0; mt < 2; ++mt)
                acc[mt][nt] = __builtin_amdgcn_mfma_f32_16x16x32_bf16(af[mt], bb.s, acc[mt][nt], 0, 0, 0);
        }
    }

    // ---- epilogue: per-quarter partial LSE (same quarter grouping as r3 - bit-identical) ----
    float y2c[4];
#pragma unroll
    for (int nt = 0; nt < 4; ++nt) y2c[nt] = y2g[v * NCLS + zq * CQ + nt * 16 + col];

    float corr = 0.f;
#pragma unroll
    for (int mt = 0; mt < 2; ++mt) {
#pragma unroll
        for (int r = 0; r < 4; ++r) {
            const int n = q0 + wave * 32 + mt * 16 + quad * 4 + r;
            const int cn = n / NQRY;
            float s[4];
            float mx = -1e30f;
#pragma unroll
            for (int nt = 0; nt < 4; ++nt) {
                s[nt] = 2.f * acc[mt][nt][r] - y2c[nt];
                mx = fmaxf(mx, s[nt]);
                if (cn == zq * CQ + nt * 16 + col) corr += s[nt];
            }
#pragma unroll
            for (int o = 1; o < 16; o <<= 1) mx = fmaxf(mx, __shfl_xor(mx, o));
            float e = 0.f;
#pragma unroll
            for (int nt = 0; nt < 4; ++nt) e += __expf(s[nt] - mx);
#pragma unroll
            for (int o = 1; o < 16; o <<= 1) e += __shfl_xor(e, o);
            if (col == 0) {
                const size_t idx = (size_t)(v * 4 + zq) * NQ_TOT + n;
                pmax_g[idx] = mx;
                pse_g[idx] = e;
            }
        }
    }
#pragma unroll
    for (int o = 1; o < 64; o <<= 1) corr += __shfl_xor(corr, o);

    __syncthreads();                    // K-loop LDS reads done -> overlay scratch
    float* wred = (float*)&p_lds[0];
    if (lane == 0) wred[wave] = corr;
    __syncthreads();
    if (t == 0) {
        float bc = wred[0] + wred[1] + wred[2] + wred[3] +
                   wred[4] + wred[5] + wred[6] + wred[7];
        atomicAdd(wsc, bc);
    }
}

// ---------- kernel 3: combine 4 quarter-partials -> LSE, reduce loss ----------
__global__ __launch_bounds__(512) void combine_kernel(const float* __restrict__ pmax_g,
                                                      const float* __restrict__ pse_g,
                                                      const float* __restrict__ wsc,
                                                      float* __restrict__ out) {
    __shared__ float wred[8];
    const int idx = blockIdx.x * 512 + threadIdx.x;   // 0..62975
    const int v = idx / NQ_TOT;
    const int n = idx - v * NQ_TOT;

    float m[4], se[4];
#pragma unroll
    for (int zq = 0; zq < 4; ++zq) {
        const size_t i = (size_t)(v * 4 + zq) * NQ_TOT + n;
        m[zq] = pmax_g[i];
        se[zq] = pse_g[i];
    }
    const float M = fmaxf(fmaxf(m[0], m[1]), fmaxf(m[2], m[3]));
    const float E = se[0] * __expf(m[0] - M) + se[1] * __expf(m[1] - M) +
                    se[2] * __expf(m[2] - M) + se[3] * __expf(m[3] - M);
    float lval = M + __logf(E);

#pragma unroll
    for (int o = 1; o < 64; o <<= 1) lval += __shfl_xor(lval, o);
    const int lane = threadIdx.x & 63, wave = threadIdx.x >> 6;
    if (lane == 0) wred[wave] = lval;
    __syncthreads();
    if (threadIdx.x == 0) {
        float bs = wred[0] + wred[1] + wred[2] + wred[3] +
                   wred[4] + wred[5] + wred[6] + wred[7];
        atomicAdd(out, bs * INV_CNT);
        if (blockIdx.x == 0) atomicAdd(out, -wsc[0] * INV_CNT);
    }
}

extern "C" void kernel_launch(void* const* d_in, const int* in_sizes, int n_in,
                              void* d_out, int out_size, void* d_ws, size_t ws_size,
                              hipStream_t stream) {
    const float* reps = (const float*)d_in[0];
    ushort* pbf = (ushort*)d_ws;                          // 393216 B
    float* y2 = (float*)(pbf + NVIEW * NCLS * DD);        // 2048 B
    float* pmax_g = y2 + NVIEW * NCLS;                    // 2*4*31488 floats
    float* pse_g = pmax_g + (size_t)NVIEW * 4 * NQ_TOT;
    float* wsc = pse_g + (size_t)NVIEW * 4 * NQ_TOT;      // 1 float
    float* out = (float*)d_out;

    proto_kernel<<<dim3(NVIEW * NCLS), dim3(DD), 0, stream>>>(reps, pbf, y2, wsc, out);
    main_kernel<<<dim3(NQ_TOT / QB, NVIEW, 4), dim3(512), 0, stream>>>(reps, pbf, y2,
                                                                       pmax_g, pse_g, wsc);
    combine_kernel<<<dim3(NVIEW * NQ_TOT / 512), dim3(512), 0, stream>>>(pmax_g, pse_g,
                                                                         wsc, out);
}

// Round 6
// 161.892 us; speedup vs baseline: 1.2161x; 1.2161x over previous
//
#include <hip/hip_runtime.h>
#include <hip/hip_bf16.h>
#include <math.h>

#define NCLS 256
#define PER_CLASS 128
#define NSUP 5
#define NQRY 123              // PER_CLASS - NSUP
#define NVIEW 2
#define DD 384
#define NQ_TOT (NCLS * NQRY)  // 31488
#define BM 128                // queries per block
#define BK 32                 // k-tile (elems)
#define NKT (DD / BK)         // 12
#define QS 40                 // Q LDS row stride in ushorts (16B-aligned; verified 0-conflict)
#define PS 32                 // P LDS row stride in ushorts (unpadded: gll writes linearly)

typedef __attribute__((ext_vector_type(8))) short short8;
typedef __attribute__((ext_vector_type(4))) float floatx4;

union FragU { uint4 u; short8 s; };
union PkU { __hip_bfloat162 b2; unsigned int u; };

__device__ __forceinline__ unsigned int cvt2bf(float lo, float hi) {
    PkU p;
    p.b2 = __float22bfloat162_rn(make_float2(lo, hi));
    return p.u;
}

// async global->LDS, 16B per lane; LDS dest = wave-uniform base + lane*16 (HW rule)
__device__ __forceinline__ void gll16(const ushort* g, ushort* l) {
    __builtin_amdgcn_global_load_lds(
        (const __attribute__((address_space(1))) unsigned int*)g,
        (__attribute__((address_space(3))) unsigned int*)l, 16, 0, 0);
}

// barrier WITHOUT the vmcnt(0) drain __syncthreads would emit.
#define BARRIER() asm volatile("s_waitcnt lgkmcnt(0)\n\ts_barrier" ::: "memory")
#define WAITVM(n) asm volatile("s_waitcnt vmcnt(" #n ")" ::: "memory")

// ---------- kernel 1: prototypes -> bf16 + y2 + out-zero ----------
__global__ __launch_bounds__(384) void proto_kernel(const float* __restrict__ reps,
                                                    ushort* __restrict__ pbf,
                                                    float* __restrict__ y2,
                                                    float* __restrict__ out) {
    __shared__ float wp[6];
    const int b = blockIdx.x;          // v*256 + c
    const int c = b & 255, v = b >> 8;
    const int d = threadIdx.x;         // 0..383
    if (b == 0 && d == 0) out[0] = 0.f;
    const float* p = reps + ((size_t)(c * PER_CLASS) * NVIEW + v) * DD + d;
    float s = 0.f;
#pragma unroll
    for (int k = 0; k < NSUP; ++k) s += p[(size_t)k * NVIEW * DD];
    s *= 0.2f;
    __hip_bfloat16 h = __float2bfloat16(s);
    pbf[(size_t)b * DD + d] = *reinterpret_cast<ushort*>(&h);
    float q = s * s;
#pragma unroll
    for (int o = 1; o < 64; o <<= 1) q += __shfl_xor(q, o);
    if ((d & 63) == 0) wp[d >> 6] = q;
    __syncthreads();
    if (d == 0) y2[b] = wp[0] + wp[1] + wp[2] + wp[3] + wp[4] + wp[5];
}

// ---------- kernel 2: 8-wave bf16 MFMA GEMM + fused logsumexp/NLL ----------
// r3 base (verified absmax 0, bank-conflict 0) with DEEPER FLIGHT:
// P: 3 LDS buffers, gll issued 3 tiles ahead, waited 2 tile-computes later (~500cy cover).
// Q: 3 register buffers, loaded 3 tiles ahead, staged 1 ahead.
// Counted vmcnt(8) mid-loop (tiles kt+2,kt+3 = 8 ops stay in flight); 0 only at tail.
__global__ __launch_bounds__(512, 4) void main_kernel(const float* __restrict__ reps,
                                                      const ushort* __restrict__ pbf,
                                                      const float* __restrict__ y2g,
                                                      float* __restrict__ out) {
    __shared__ ushort q_lds[2][BM * QS];    // 2 x 10240 B
    __shared__ ushort p_lds[3][NCLS * PS];  // 3 x 16384 B  (epilogue overlays p_lds[0])

    const int t = threadIdx.x;
    const int v = blockIdx.y;
    const int q0 = blockIdx.x * BM;
    const int wave = t >> 6;
    const int lane = t & 63;
    const int col = lane & 15;   // MFMA m/n index
    const int quad = lane >> 4;  // MFMA k-chunk / C row group
    const int wm = wave >> 2;    // query half  (0..1)
    const int wn = wave & 3;     // class quarter (0..3)

    // Q staging map: 4 threads/row (t>>2 = row, (t&3)*8 = float offset)
    const int sq = t >> 2;
    const int f8 = (t & 3) * 8;
    const int nq = q0 + sq;
    const float* qsrc = reps +
        (size_t)((nq / NQRY) * PER_CLASS + NSUP + (nq % NQRY)) * (NVIEW * DD) + v * DD + f8;

    // P gll map: wave w stages rows 32w..32w+31 (2 calls x 16 rows).
    // lane l -> row 32w+16i+(l>>2), phys chunk (l&3); source chunk-XOR-swizzled so phys
    // chunk c holds data chunk c ^ ((row>>1)&3); read phys = quad ^ ((col>>1)&3).
    // [verified r1/r3: absmax 0, SQ_LDS_BANK_CONFLICT 0]
    const ushort* psrc = pbf + (size_t)(v * NCLS + wave * 32 + (lane >> 2)) * DD
                             + (((lane & 3) ^ ((lane >> 3) & 3)) << 3);

    const int sP = (col >> 1) & 3;
    const int pbase = (wn * 64 + col) * PS + ((quad ^ sP) << 3);  // + nt*16*PS as imm

    floatx4 acc[4][4];
#pragma unroll
    for (int mt = 0; mt < 4; ++mt)
#pragma unroll
        for (int nt = 0; nt < 4; ++nt) acc[mt][nt] = (floatx4)0.f;

    float4 qfA[2], qfB[2], qfC[2];

#define LOADQ(kt, R)                                                               \
    do {                                                                           \
        R[0] = *(const float4*)(qsrc + (kt) * BK);                                 \
        R[1] = *(const float4*)(qsrc + (kt) * BK + 4);                             \
    } while (0)

#define GLLP(kt, b)                                                                \
    do {                                                                           \
        gll16(psrc + (kt) * BK, &p_lds[b][wave * 1024]);                           \
        gll16(psrc + 16 * DD + (kt) * BK, &p_lds[b][wave * 1024 + 512]);           \
    } while (0)

#define STAGEQ(b, R)                                                               \
    do {                                                                           \
        uint4 w;                                                                   \
        w.x = cvt2bf(R[0].x, R[0].y); w.y = cvt2bf(R[0].z, R[0].w);                \
        w.z = cvt2bf(R[1].x, R[1].y); w.w = cvt2bf(R[1].z, R[1].w);                \
        *(uint4*)&q_lds[b][sq * QS + f8] = w;                                      \
    } while (0)

#define COMPUTE(qb, pb)                                                            \
    do {                                                                           \
        short8 af[4];                                                              \
        _Pragma("unroll") for (int mt = 0; mt < 4; ++mt) {                         \
            FragU f;                                                               \
            f.u = *(const uint4*)&q_lds[qb][(wm * 64 + mt * 16 + col) * QS + quad * 8]; \
            af[mt] = f.s;                                                          \
        }                                                                          \
        _Pragma("unroll") for (int nt = 0; nt < 4; ++nt) {                         \
            FragU bb;                                                              \
            bb.u = *(const uint4*)&p_lds[pb][pbase + nt * 16 * PS];                \
            _Pragma("unroll") for (int mt = 0; mt < 4; ++mt)                       \
                acc[mt][nt] = __builtin_amdgcn_mfma_f32_16x16x32_bf16(af[mt], bb.s, acc[mt][nt], 0, 0, 0); \
        }                                                                          \
    } while (0)

    // ---- prologue: tiles 0,1,2 in flight (4 VMEM ops each, FIFO per tile) ----
    LOADQ(0, qfA); GLLP(0, 0);
    LOADQ(1, qfB); GLLP(1, 1);
    LOADQ(2, qfC); GLLP(2, 2);
    WAITVM(8);          // tile-0 ops landed; tiles 1,2 (8 ops) stay in flight
    STAGEQ(0, qfA);
    BARRIER();          // tile 0 ready

#pragma unroll
    for (int kt = 0; kt < NKT; ++kt) {
        COMPUTE(kt & 1, kt % 3);
        if (kt == NKT - 1) break;
        BARRIER();      // readers done with q_lds[kt&1], p_lds[kt%3]
        if (kt < NKT - 3) {
            // issue tile kt+3 into the buffers just freed
            if (kt % 3 == 0)      LOADQ(kt + 3, qfA);
            else if (kt % 3 == 1) LOADQ(kt + 3, qfB);
            else                  LOADQ(kt + 3, qfC);
            GLLP(kt + 3, kt % 3);
            WAITVM(8);  // drains tile kt+1 (issued 2 computes ago); kt+2,kt+3 stay in flight
        } else if (kt == NKT - 3) {
            WAITVM(4);  // target tile kt+1; only tile kt+2 (4 ops) newer
        } else {
            WAITVM(0);  // kt == NKT-2: target tile kt+1 is newest
        }
        if ((kt + 1) % 3 == 0)      STAGEQ((kt + 1) & 1, qfA);
        else if ((kt + 1) % 3 == 1) STAGEQ((kt + 1) & 1, qfB);
        else                        STAGEQ((kt + 1) & 1, qfC);
        BARRIER();      // publish tile kt+1 (each wave vmcnt-waited its own gll above)
    }

    // ---- epilogue (r3-verified; scratch overlays p_lds[0]) ----
    __syncthreads();    // retire all K-loop LDS reads before overlay writes
    float* eplds = (float*)&p_lds[0][0];
    float (*pmx)[4] = (float(*)[4])eplds;            // 128 x 4
    float (*pse)[4] = (float(*)[4])(eplds + 512);    // 128 x 4
    float* wred = eplds + 1024;                      // 16

    float y2c[4];
#pragma unroll
    for (int nt = 0; nt < 4; ++nt) y2c[nt] = y2g[v * NCLS + wn * 64 + nt * 16 + col];

    float corr = 0.f;
#pragma unroll
    for (int mt = 0; mt < 4; ++mt) {
#pragma unroll
        for (int r = 0; r < 4; ++r) {
            const int qloc = wm * 64 + mt * 16 + quad * 4 + r;
            const int n = q0 + qloc;
            const int cn = n / NQRY;
            float s[4];
            float mx = -1e30f;
#pragma unroll
            for (int nt = 0; nt < 4; ++nt) {
                s[nt] = 2.f * acc[mt][nt][r] - y2c[nt];
                mx = fmaxf(mx, s[nt]);
                if (cn == wn * 64 + nt * 16 + col) corr += s[nt];
            }
#pragma unroll
            for (int o = 1; o < 16; o <<= 1) mx = fmaxf(mx, __shfl_xor(mx, o));
            float e = 0.f;
#pragma unroll
            for (int nt = 0; nt < 4; ++nt) e += __expf(s[nt] - mx);
#pragma unroll
            for (int o = 1; o < 16; o <<= 1) e += __shfl_xor(e, o);
            if (col == 0) { pmx[qloc][wn] = mx; pse[qloc][wn] = e; }
        }
    }
#pragma unroll
    for (int o = 1; o < 64; o <<= 1) corr += __shfl_xor(corr, o);
    if (lane == 0) wred[wave] = corr;
    __syncthreads();

    float lval = 0.f;
    if (t < BM) {
        float m0 = pmx[t][0], m1 = pmx[t][1], m2 = pmx[t][2], m3 = pmx[t][3];
        float M = fmaxf(fmaxf(m0, m1), fmaxf(m2, m3));
        float E = pse[t][0] * __expf(m0 - M) + pse[t][1] * __expf(m1 - M) +
                  pse[t][2] * __expf(m2 - M) + pse[t][3] * __expf(m3 - M);
        lval = M + __logf(E);
    }
#pragma unroll
    for (int o = 1; o < 64; o <<= 1) lval += __shfl_xor(lval, o);
    if (lane == 0) wred[8 + wave] = lval;
    __syncthreads();

    if (t == 0) {
        float tot = (wred[8] + wred[9] + wred[10] + wred[11] +
                     wred[12] + wred[13] + wred[14] + wred[15]) -
                    (wred[0] + wred[1] + wred[2] + wred[3] +
                     wred[4] + wred[5] + wred[6] + wred[7]);
        atomicAdd(out, tot * (1.f / (float)(NQ_TOT * NVIEW)));
    }
}

extern "C" void kernel_launch(void* const* d_in, const int* in_sizes, int n_in,
                              void* d_out, int out_size, void* d_ws, size_t ws_size,
                              hipStream_t stream) {
    const float* reps = (const float*)d_in[0];
    float* ws = (float*)d_ws;
    ushort* pbf = (ushort*)ws;                      // 196608 ushorts
    float* y2 = (float*)(pbf + NVIEW * NCLS * DD);  // 512 floats
    float* out = (float*)d_out;

    proto_kernel<<<dim3(NVIEW * NCLS), dim3(DD), 0, stream>>>(reps, pbf, y2, out);
    main_kernel<<<dim3(NQ_TOT / BM, NVIEW), dim3(512), 0, stream>>>(reps, pbf, y2, out);
}